// Round 11
// baseline (302.812 us; speedup 1.0000x reference)
//
#include <hip/hip_runtime.h>
#include <math.h>

#define TWO_N 8192
#define NR 4096
#define D 256
#define PMW 128  // u64 mask words per row
#define L2E 1.44269504088896340736f

typedef __attribute__((ext_vector_type(8))) short bf16x8;
typedef __attribute__((ext_vector_type(4))) float f32x4;

#define AS1V const __attribute__((address_space(1))) void
#define AS3V __attribute__((address_space(3))) void
#define WAITVM(n) asm volatile("s_waitcnt vmcnt(" #n ")" ::: "memory")

__device__ inline unsigned short f2bf(float x) {
  unsigned u = __builtin_bit_cast(unsigned, x);
  u += 0x7fffu + ((u >> 16) & 1u);  // RNE
  return (unsigned short)(u >> 16);
}

__device__ inline float exp2_hw(float x) {
  float r;
  asm("v_exp_f32 %0, %1" : "=v"(r) : "v"(x));
  return r;
}

// Fused prep: [0,1024) cvt f32->bf16; [1024,3072) mask byte->bit repack;
// [3072,4096) apl[i] = -dot(e_i, e_{i+NR})*log2e + rowsum/rowsum2 zero.
__global__ __launch_bounds__(256) void prep_kernel(
    const float* __restrict__ emb, const unsigned char* __restrict__ negm,
    unsigned short* __restrict__ ebf, unsigned long long* __restrict__ pm,
    float* __restrict__ apl, double* __restrict__ rowsum, double* __restrict__ rowsum2) {
  const int b = blockIdx.x, t = threadIdx.x;
  if (b < 1024) {
    const size_t i = ((size_t)b * 256 + t) * 8;
    const float4 a = *reinterpret_cast<const float4*>(emb + i);
    const float4 c = *reinterpret_cast<const float4*>(emb + i + 4);
    union { unsigned short s[8]; bf16x8 v; } o;
    o.s[0] = f2bf(a.x); o.s[1] = f2bf(a.y); o.s[2] = f2bf(a.z); o.s[3] = f2bf(a.w);
    o.s[4] = f2bf(c.x); o.s[5] = f2bf(c.y); o.s[6] = f2bf(c.z); o.s[7] = f2bf(c.w);
    *reinterpret_cast<bf16x8*>(ebf + i) = o.v;
  } else if (b < 3072) {
    const int w = (b - 1024) * 256 + t;  // u64 word index
    const uint4* p = reinterpret_cast<const uint4*>(negm + (size_t)w * 64);
    unsigned long long acc = 0;
#pragma unroll
    for (int q = 0; q < 4; ++q) {
      const uint4 v = p[q];
      unsigned bb = 0;
      bb |= (v.x & 1u) | ((v.x >> 7) & 2u) | ((v.x >> 14) & 4u) | ((v.x >> 21) & 8u);
      bb |= ((v.y & 1u) | ((v.y >> 7) & 2u) | ((v.y >> 14) & 4u) | ((v.y >> 21) & 8u)) << 4;
      bb |= ((v.z & 1u) | ((v.z >> 7) & 2u) | ((v.z >> 14) & 4u) | ((v.z >> 21) & 8u)) << 8;
      bb |= ((v.w & 1u) | ((v.w >> 7) & 2u) | ((v.w >> 14) & 4u) | ((v.w >> 21) & 8u)) << 12;
      acc |= (unsigned long long)bb << (q * 16);
    }
    pm[w] = acc;
  } else {
    const int lane = t & 63, wid = t >> 6;
    const int i = (b - 3072) * 4 + wid;
    const float4 a = *reinterpret_cast<const float4*>(emb + (size_t)i * D + lane * 4);
    const float4 c = *reinterpret_cast<const float4*>(emb + (size_t)(i + NR) * D + lane * 4);
    float s = a.x * c.x + a.y * c.y + a.z * c.z + a.w * c.w;
#pragma unroll
    for (int off = 32; off >= 1; off >>= 1) s += __shfl_xor(s, off, 64);
    if (lane == 0) { apl[i] = -s * L2E; rowsum[i] = 0.0; rowsum2[i] = 0.0; }
  }
}

// One block per CU (grid 256, 512 thr): 128-row panel x 1024 cols (4 bj of 256).
// A whole-K resident (64 KB); B 2-slot ring (2x32 KB); waves 2x4, tile 64x64.
// Counted vmcnt(4): tile gkt+1 always in flight during compute of gkt.
// NOTE round 11: launched TWICE (second into scratch rowsum2) purely to make
// this kernel's duration directly readable as T11 - T10 (top-5 slots are all
// taken by the harness's 78us ws-poison fills, so fused is otherwise invisible).
__global__ __launch_bounds__(512) void fused_mfma(
    const unsigned short* __restrict__ ebf, const unsigned long long* __restrict__ pm,
    const float* __restrict__ apl, double* __restrict__ rowsum) {
  __shared__ unsigned short As[4][128 * 64];  // 64 KB
  __shared__ unsigned short Bs[2][256 * 64];  // 64 KB
  const int t = threadIdx.x, lane = t & 63, wid = t >> 6;
  const int wr = wid >> 2, wc = wid & 3;  // 2x4 wave grid, 64x64 per wave
  const int bi = blockIdx.x >> 3;   // 0..31 row panel
  const int chunk = blockIdx.x & 7; // 0..7 B-chunk == XCD id
  const int g = lane >> 4, cl = lane & 15;
  const int srow = lane >> 3;
  const int sc8 = ((lane & 7) ^ srow) * 8;  // inverse-swizzled source chunk (r7-verified)

  // Row constants (oldest VMEM, retired before first WAITVM target).
  float apv[4][4];
#pragma unroll
  for (int m = 0; m < 4; ++m) {
    const float4 v = *reinterpret_cast<const float4*>(apl + bi * 128 + wr * 64 + m * 16 + g * 4);
    apv[m][0] = v.x; apv[m][1] = v.y; apv[m][2] = v.z; apv[m][3] = v.w;
  }

  // A panel: 4 kt slots x 2 instr/wave (8 rows each).
#pragma unroll
  for (int kt = 0; kt < 4; ++kt)
#pragma unroll
    for (int q = 0; q < 2; ++q) {
      const int rbase = wid * 16 + q * 8;
      const unsigned short* gp = ebf + (size_t)(bi * 128 + rbase + srow) * D + kt * 64 + sc8;
      __builtin_amdgcn_global_load_lds((AS1V*)gp, (AS3V*)(As[kt] + rbase * 64), 16, 0, 0);
    }

  auto STAGEB = [&](int gk) {  // B tile gk (bj = gk>>2, kt = gk&3) -> slot gk&1; 4 instr/wave
    const int kt = gk & 3, bjj = gk >> 2;
#pragma unroll
    for (int q = 0; q < 4; ++q) {
      const int rbase = wid * 32 + q * 8;
      const unsigned short* gp =
          ebf + (size_t)(chunk * 1024 + bjj * 256 + rbase + srow) * D + kt * 64 + sc8;
      __builtin_amdgcn_global_load_lds((AS1V*)gp, (AS3V*)(Bs[gk & 1] + rbase * 64), 16, 0, 0);
    }
  };
  STAGEB(0); STAGEB(1);

  double rs[4][4] = {};

  for (int bj = 0; bj < 4; ++bj) {
    f32x4 acc[4][4] = {};
    unsigned long long mw[4][4];
#pragma unroll
    for (int kt = 0; kt < 4; ++kt) {
      const int gkt = bj * 4 + kt;
      // Tile gkt must be landed; tile gkt+1 (4 instr, newest) may stay in flight.
      if (kt == 3) { if (bj == 3) { WAITVM(0); } else { WAITVM(4); } }
      else { WAITVM(4); }
      __builtin_amdgcn_s_barrier();
      __builtin_amdgcn_sched_barrier(0);
      __builtin_amdgcn_s_setprio(1);
#pragma unroll
      for (int kk = 0; kk < 2; ++kk) {
        const int cswz = ((kk * 4 + g) ^ (lane & 7)) * 8;
        bf16x8 af[4], bf[4];
#pragma unroll
        for (int m = 0; m < 4; ++m)
          af[m] = *reinterpret_cast<const bf16x8*>(&As[kt][(wr * 64 + m * 16 + cl) * 64 + cswz]);
#pragma unroll
        for (int n = 0; n < 4; ++n)
          bf[n] = *reinterpret_cast<const bf16x8*>(&Bs[gkt & 1][(wc * 64 + n * 16 + cl) * 64 + cswz]);
#pragma unroll
        for (int m = 0; m < 4; ++m)
#pragma unroll
          for (int n = 0; n < 4; ++n)
            acc[m][n] = __builtin_amdgcn_mfma_f32_16x16x32_bf16(af[m], bf[n], acc[m][n], 0, 0, 0);
      }
      __builtin_amdgcn_s_setprio(0);
      __builtin_amdgcn_s_barrier();  // ring WAR: all waves done with slot gkt&1
      __builtin_amdgcn_sched_barrier(0);
      if (kt == 3) {  // pm loads BEFORE the stage: newest-4 invariant holds
#pragma unroll
        for (int m = 0; m < 4; ++m)
#pragma unroll
          for (int r2 = 0; r2 < 4; ++r2) {
            const int row = bi * 128 + wr * 64 + m * 16 + g * 4 + r2;
            mw[m][r2] = pm[(size_t)row * PMW + chunk * 16 + bj * 4 + wc];
          }
        __builtin_amdgcn_sched_barrier(0);
      }
      if (gkt + 2 < 16) STAGEB(gkt + 2);  // writes slot gkt&1, safe after barrier
      __builtin_amdgcn_sched_barrier(0);
    }
    // Epilogue for bj: e^x = 2^frac * 2^k, k via integer exponent-bit build
    // (no libcall), f64 fma accumulate. Clamp keeps 1023+k in (0,2046) -> finite.
#pragma unroll
    for (int m = 0; m < 4; ++m)
#pragma unroll
      for (int n = 0; n < 4; ++n)
#pragma unroll
        for (int r2 = 0; r2 < 4; ++r2) {
          float tt = fmaf(acc[m][n][r2], L2E, apv[m][r2]);
          tt = fminf(fmaxf(tt, -1020.f), 1000.f);
          const float kf = floorf(tt);
          const float mant = exp2_hw(tt - kf);
          const float mm = ((mw[m][r2] >> (n * 16 + cl)) & 1) ? mant : 0.f;
          const long long ebits = (long long)(1023 + (int)kf) << 52;
          rs[m][r2] += (double)mm * __builtin_bit_cast(double, ebits);
        }
  }

  // Reduce over the 16 col-lanes sharing each row; one f64 atomic per row per wave.
#pragma unroll
  for (int m = 0; m < 4; ++m)
#pragma unroll
    for (int r2 = 0; r2 < 4; ++r2) {
      double v = rs[m][r2];
#pragma unroll
      for (int off = 8; off >= 1; off >>= 1) v += __shfl_xor(v, off, 64);
      if (cl == 0) atomicAdd(&rowsum[bi * 128 + wr * 64 + m * 16 + g * 4 + r2], v);
    }
}

// j_i = log1p(rowsum_i) in f64 (finite by construction); mean over rows.
__global__ __launch_bounds__(1024) void finalize_kernel(const double* __restrict__ rowsum,
                                                        float* __restrict__ out) {
  __shared__ double red[16];
  const int t = threadIdx.x;
  double s = 0.0;
#pragma unroll
  for (int k = 0; k < 4; ++k) s += log1p(rowsum[t + k * 1024]);
#pragma unroll
  for (int off = 32; off >= 1; off >>= 1) s += __shfl_xor(s, off, 64);
  if ((t & 63) == 0) red[t >> 6] = s;
  __syncthreads();
  if (t == 0) {
    double tot = 0.0;
#pragma unroll
    for (int w = 0; w < 16; ++w) tot += red[w];
    out[0] = (float)(tot * (1.0 / NR));
  }
}

extern "C" void kernel_launch(void* const* d_in, const int* in_sizes, int n_in,
                              void* d_out, int out_size, void* d_ws, size_t ws_size,
                              hipStream_t stream) {
  const float* emb = (const float*)d_in[0];
  // d_in[1] (pos_mask) unused by the reference.
  const unsigned char* negm = (const unsigned char*)d_in[2];
  float* out = (float*)d_out;
  char* ws = (char*)d_ws;
  unsigned short* ebf = (unsigned short*)ws;                        // 4 MB bf16 embeddings
  unsigned long long* pm = (unsigned long long*)(ws + (1u << 22));  // 4 MB packed mask
  float* apl = (float*)(ws + (2u << 22));                           // 16 KB (-ap*log2e)
  double* rowsum = (double*)(ws + (2u << 22) + 16384);              // 32 KB
  double* rowsum2 = (double*)(ws + (2u << 22) + 16384 + 32768);     // 32 KB scratch (timing probe)

  prep_kernel<<<dim3(4096), dim3(256), 0, stream>>>(emb, negm, ebf, pm, apl, rowsum, rowsum2);
  fused_mfma<<<dim3(256), dim3(512), 0, stream>>>(ebf, pm, apl, rowsum);
  // Timing probe: identical second dispatch into scratch; stream order serializes,
  // so total graph time grows by exactly one fused_mfma duration.
  fused_mfma<<<dim3(256), dim3(512), 0, stream>>>(ebf, pm, apl, rowsum2);
  finalize_kernel<<<dim3(1), dim3(1024), 0, stream>>>(rowsum, out);
}